// Round 1
// baseline (99.990 us; speedup 1.0000x reference)
//
#include <hip/hip_runtime.h>

#define NLEV 25

typedef float v4f __attribute__((ext_vector_type(4)));

struct QR { float hard; float sym; };

__device__ __forceinline__ QR quantize_one(float v, const float* __restrict__ lvl) {
    // candidate index on the uniform grid levels[j] ~= -2 + j/6
    float fc = rintf(fmaf(v, 6.0f, 12.0f));
    fc = fminf(fmaxf(fc, 0.0f), 24.0f);   // v_med3 clamp
    int c  = (int)fc;
    int j0 = max(c - 1, 0);
    int j2 = min(c + 1, NLEV - 1);

    // exact fp32 argmin over the 3-candidate window, increasing-index strict-<
    // scan == numpy first-index tie-break; level values are the exact stored
    // linspace values (LDS), so x_hard/symbols are bit-exact vs reference.
    float l0 = lvl[j0];
    float d0 = (v - l0) * (v - l0);
    int   best  = j0;
    float lbest = l0;
    float dbest = d0;

    float l1 = lvl[c];
    float d1 = (v - l1) * (v - l1);
    if (d1 < dbest) { dbest = d1; best = c; lbest = l1; }

    float l2 = lvl[j2];
    float d2 = (v - l2) * (v - l2);
    if (d2 < dbest) { dbest = d2; best = j2; lbest = l2; }

    QR r; r.hard = lbest; r.sym = (float)best;
    return r;
}

__device__ __forceinline__ void process_store(
    v4f xv, int idx, const float* __restrict__ lvl,
    v4f* __restrict__ o_ste, v4f* __restrict__ o_hrd, v4f* __restrict__ o_sym)
{
    QR q0 = quantize_one(xv.x, lvl);
    QR q1 = quantize_one(xv.y, lvl);
    QR q2 = quantize_one(xv.z, lvl);
    QR q3 = quantize_one(xv.w, lvl);
    v4f hv = {q0.hard, q1.hard, q2.hard, q3.hard};
    v4f sv = {q0.sym,  q1.sym,  q2.sym,  q3.sym};
    // R(this): NT on STORES ONLY. Theory: ~35us kernel residual is RFO on the
    // 75.5 MB store streams (100 MB mandatory + ~75 MB write-allocate fetch
    // ~= 200+ MB ~= 35us). R3's NT regression flipped loads too, which loses
    // L3 hits on x (restore copy re-warms it every iter) — that cell was
    // confounded. Loads stay cached.
    __builtin_nontemporal_store(hv, &o_ste[idx]);   // x_ste forward == x_hard (STE)
    __builtin_nontemporal_store(hv, &o_hrd[idx]);
    __builtin_nontemporal_store(sv, &o_sym[idx]);
}

// Four float4s per thread, all four loads issued before any compute:
// 64 B/lane outstanding VMEM. Cached loads: the harness's restore copy
// warms L2/L3 with x. 1536 blocks -> 24 waves/CU.
__global__ __launch_bounds__(256) void soft_quant_vec4x4(
    const float* __restrict__ x,
    const float* __restrict__ levels,
    float* __restrict__ out,   // [3*n]: x_ste | x_hard | symbols(as float)
    int n)
{
    __shared__ float lvl[NLEV];
    if (threadIdx.x < NLEV) lvl[threadIdx.x] = levels[threadIdx.x];
    __syncthreads();

    const int n4 = n >> 2;
    const v4f* __restrict__ x4 = reinterpret_cast<const v4f*>(x);
    v4f* __restrict__ o_ste = reinterpret_cast<v4f*>(out);
    v4f* __restrict__ o_hrd = reinterpret_cast<v4f*>(out + n);
    v4f* __restrict__ o_sym = reinterpret_cast<v4f*>(out + 2 * n);

    int base = blockIdx.x * (blockDim.x * 4) + threadIdx.x;
    int i0 = base;
    int i1 = base + blockDim.x;
    int i2 = base + blockDim.x * 2;
    int i3 = base + blockDim.x * 3;
    bool v0 = i0 < n4, v1 = i1 < n4, v2 = i2 < n4, v3 = i3 < n4;

    v4f x0, x1, x2, x3;
    if (v0) x0 = x4[i0];
    if (v1) x1 = x4[i1];
    if (v2) x2 = x4[i2];
    if (v3) x3 = x4[i3];

    if (v0) process_store(x0, i0, lvl, o_ste, o_hrd, o_sym);
    if (v1) process_store(x1, i1, lvl, o_ste, o_hrd, o_sym);
    if (v2) process_store(x2, i2, lvl, o_ste, o_hrd, o_sym);
    if (v3) process_store(x3, i3, lvl, o_ste, o_hrd, o_sym);
}

// scalar tail (defensive; n is divisible by 4 for this problem)
__global__ void soft_quant_tail(
    const float* __restrict__ x,
    const float* __restrict__ levels,
    float* __restrict__ out,
    int start, int n)
{
    int i = start + blockIdx.x * blockDim.x + threadIdx.x;
    if (i >= n) return;
    float v = x[i];
    float fc = rintf(fmaf(v, 6.0f, 12.0f));
    fc = fminf(fmaxf(fc, 0.0f), 24.0f);
    int c = (int)fc;
    int j0 = max(c - 1, 0);
    int j2 = min(c + 1, NLEV - 1);
    int best = j0;
    float lbest = levels[j0];
    float dbest = (v - lbest) * (v - lbest);
    for (int j = j0 + 1; j <= j2; ++j) {
        float lj = levels[j];
        float dj = (v - lj) * (v - lj);
        if (dj < dbest) { dbest = dj; best = j; lbest = lj; }
    }
    out[i]         = lbest;
    out[n + i]     = lbest;
    out[2 * n + i] = (float)best;
}

extern "C" void kernel_launch(void* const* d_in, const int* in_sizes, int n_in,
                              void* d_out, int out_size, void* d_ws, size_t ws_size,
                              hipStream_t stream) {
    const float* x      = (const float*)d_in[0];
    const float* levels = (const float*)d_in[1];
    float* out          = (float*)d_out;
    const int n  = in_sizes[0];
    const int n4 = n >> 2;

    const int block = 256;
    const int per_block = block * 4;            // four float4s per thread
    if (n4 > 0) {
        int grid = (n4 + per_block - 1) / per_block;
        soft_quant_vec4x4<<<grid, block, 0, stream>>>(x, levels, out, n);
    }
    int tail = n - (n4 << 2);
    if (tail > 0) {
        soft_quant_tail<<<1, 64, 0, stream>>>(x, levels, out, n4 << 2, n);
    }
}

// Round 2
// 95.150 us; speedup vs baseline: 1.0509x; 1.0509x over previous
//
#include <hip/hip_runtime.h>

#define NLEV 25
#define SENTINEL 3.4028235e38f  // FLT_MAX: (v-SENTINEL)^2 = inf, never wins argmin

typedef float v4f __attribute__((ext_vector_type(4)));

struct QR { float hard; float sym; };

// tab[k] = levels[k-1] for k in [1,25]; tab[0] = tab[26] = SENTINEL.
// Candidates are unconditionally c-1, c, c+1 (sentinels absorb the edges),
// killing the per-element index clamps. Strict-< increasing scan over the
// rounded squared distances == numpy first-index argmin tie-break; levels are
// the exact stored linspace values, so x_hard/symbols stay bit-exact.
__device__ __forceinline__ QR quantize_one(float v, const float* __restrict__ tab) {
    float fc = rintf(fmaf(v, 6.0f, 12.0f));
    fc = fminf(fmaxf(fc, 0.0f), 24.0f);   // v_med3 clamp
    int c = (int)fc;

    float l0 = tab[c];       // levels[c-1] (or sentinel at c==0)
    float l1 = tab[c + 1];   // levels[c]
    float l2 = tab[c + 2];   // levels[c+1] (or sentinel at c==24)

    float d0 = (v - l0) * (v - l0);
    float d1 = (v - l1) * (v - l1);
    float d2 = (v - l2) * (v - l2);

    float sym   = fc - 1.0f;
    float lbest = l0;
    float dbest = d0;
    if (d1 < dbest) { dbest = d1; lbest = l1; sym = fc; }
    if (d2 < dbest) {            lbest = l2; sym = fc + 1.0f; }

    QR r; r.hard = lbest; r.sym = sym;
    return r;
}

__device__ __forceinline__ void process_store(
    v4f xv, int idx, const float* __restrict__ tab,
    v4f* __restrict__ o_ste, v4f* __restrict__ o_hrd, v4f* __restrict__ o_sym)
{
    QR q0 = quantize_one(xv.x, tab);
    QR q1 = quantize_one(xv.y, tab);
    QR q2 = quantize_one(xv.z, tab);
    QR q3 = quantize_one(xv.w, tab);
    v4f hv = {q0.hard, q1.hard, q2.hard, q3.hard};
    v4f sv = {q0.sym,  q1.sym,  q2.sym,  q3.sym};
    // Cached (not NT) stores: R1 measured NT stores at +5.8 us — full-line
    // wave stores already elide RFO, and NT forfeits L2/L3 write absorption.
    o_ste[idx] = hv;   // x_ste forward value == x_hard (STE)
    o_hrd[idx] = hv;
    o_sym[idx] = sv;
}

// Four float4s per thread, all four loads issued before any compute:
// 64 B/lane outstanding VMEM. Cached loads: restore copy warms L2/L3 with x.
// 1536 blocks -> 24 waves/CU, all resident in one shot.
__global__ __launch_bounds__(256) void soft_quant_vec4x4(
    const float* __restrict__ x,
    const float* __restrict__ levels,
    float* __restrict__ out,   // [3*n]: x_ste | x_hard | symbols(as float)
    int n)
{
    __shared__ float tab[NLEV + 2];
    {
        int t = threadIdx.x;
        if (t < NLEV) tab[t + 1] = levels[t];
        if (t == NLEV) { tab[0] = SENTINEL; tab[NLEV + 1] = SENTINEL; }
    }
    __syncthreads();

    const int n4 = n >> 2;
    const v4f* __restrict__ x4 = reinterpret_cast<const v4f*>(x);
    v4f* __restrict__ o_ste = reinterpret_cast<v4f*>(out);
    v4f* __restrict__ o_hrd = reinterpret_cast<v4f*>(out + n);
    v4f* __restrict__ o_sym = reinterpret_cast<v4f*>(out + 2 * n);

    int base = blockIdx.x * (blockDim.x * 4) + threadIdx.x;
    int i0 = base;
    int i1 = base + blockDim.x;
    int i2 = base + blockDim.x * 2;
    int i3 = base + blockDim.x * 3;
    bool v0 = i0 < n4, v1 = i1 < n4, v2 = i2 < n4, v3 = i3 < n4;

    v4f x0, x1, x2, x3;
    if (v0) x0 = x4[i0];
    if (v1) x1 = x4[i1];
    if (v2) x2 = x4[i2];
    if (v3) x3 = x4[i3];

    if (v0) process_store(x0, i0, tab, o_ste, o_hrd, o_sym);
    if (v1) process_store(x1, i1, tab, o_ste, o_hrd, o_sym);
    if (v2) process_store(x2, i2, tab, o_ste, o_hrd, o_sym);
    if (v3) process_store(x3, i3, tab, o_ste, o_hrd, o_sym);
}

// scalar tail (defensive; n is divisible by 4 for this problem)
__global__ void soft_quant_tail(
    const float* __restrict__ x,
    const float* __restrict__ levels,
    float* __restrict__ out,
    int start, int n)
{
    int i = start + blockIdx.x * blockDim.x + threadIdx.x;
    if (i >= n) return;
    float v = x[i];
    float fc = rintf(fmaf(v, 6.0f, 12.0f));
    fc = fminf(fmaxf(fc, 0.0f), 24.0f);
    int c = (int)fc;
    int j0 = max(c - 1, 0);
    int j2 = min(c + 1, NLEV - 1);
    int best = j0;
    float lbest = levels[j0];
    float dbest = (v - lbest) * (v - lbest);
    for (int j = j0 + 1; j <= j2; ++j) {
        float lj = levels[j];
        float dj = (v - lj) * (v - lj);
        if (dj < dbest) { dbest = dj; best = j; lbest = lj; }
    }
    out[i]         = lbest;
    out[n + i]     = lbest;
    out[2 * n + i] = (float)best;
}

extern "C" void kernel_launch(void* const* d_in, const int* in_sizes, int n_in,
                              void* d_out, int out_size, void* d_ws, size_t ws_size,
                              hipStream_t stream) {
    const float* x      = (const float*)d_in[0];
    const float* levels = (const float*)d_in[1];
    float* out          = (float*)d_out;
    const int n  = in_sizes[0];
    const int n4 = n >> 2;

    const int block = 256;
    const int per_block = block * 4;            // four float4s per thread
    if (n4 > 0) {
        int grid = (n4 + per_block - 1) / per_block;
        soft_quant_vec4x4<<<grid, block, 0, stream>>>(x, levels, out, n);
    }
    int tail = n - (n4 << 2);
    if (tail > 0) {
        soft_quant_tail<<<1, 64, 0, stream>>>(x, levels, out, n4 << 2, n);
    }
}